// Round 1
// baseline (153.559 us; speedup 1.0000x reference)
//
#include <hip/hip_runtime.h>
#include <hip/hip_bf16.h>

// Problem constants
#define N_ROWS 8192
#define D_DIM  1024
#define HALF_N 4096
// Ragged cover of the upper triangle with 128(row) x 256(col) tiles:
// row-tile I in [0,64), col-tile J in [I>>1, 32).  Count = 1056.
#define N_TILES 1056
#define N_RED  8                 // parallel loss-reduction blocks
constexpr float INV_T = 1.0f / 0.07f;   // 14.2857143 — also the fixed softmax max M

typedef __attribute__((ext_vector_type(4))) float f32x4;
typedef __attribute__((ext_vector_type(2))) long long2_;   // 16B = one ds_read_b128

// async global->LDS, 16B/lane. LDS dest is wave-uniform base + lane*16.
__device__ __forceinline__ void async_ld16(const void* g, void* lds) {
    __builtin_amdgcn_global_load_lds(
        (const __attribute__((address_space(1))) void*)g,
        (__attribute__((address_space(3))) void*)lds,
        16, 0, 0);
}

// pack 4 floats -> 4 OCP e4m3 bytes in one dword
__device__ __forceinline__ unsigned int pk_fp8x4(float a, float b, float c, float d) {
    int v = __builtin_amdgcn_cvt_pk_fp8_f32(a, b, 0, false);   // bytes 0,1
    v = __builtin_amdgcn_cvt_pk_fp8_f32(c, d, v, true);        // bytes 2,3
    return (unsigned int)v;
}

// ---------------------------------------------------------------------------
// Kernel 1: row norms + fp8 e4m3 normalized copy + zeroing of row_sum and the
// handshake cells. One wave per row. (unchanged — measured fine)
__global__ __launch_bounds__(256) void norm_kernel(const float* __restrict__ feat,
                                                   unsigned char* __restrict__ fn8,
                                                   float* __restrict__ row_sum,
                                                   unsigned int* __restrict__ done_cnt,
                                                   unsigned int* __restrict__ fin_cnt,
                                                   float* __restrict__ loss_acc) {
    const int w = threadIdx.x >> 6, lane = threadIdx.x & 63;
    const int row = blockIdx.x * 4 + w;
    if (blockIdx.x == 0 && threadIdx.x == 0) {
        *done_cnt = 0u;
        *fin_cnt = 0u;
        *loss_acc = 0.f;
    }
    const float4* src = (const float4*)(feat + (size_t)row * D_DIM);
    float4 v[4];
    float ss = 0.f;
#pragma unroll
    for (int t = 0; t < 4; ++t) {
        v[t] = src[lane + 64 * t];
        ss += v[t].x * v[t].x + v[t].y * v[t].y + v[t].z * v[t].z + v[t].w * v[t].w;
    }
#pragma unroll
    for (int off = 32; off; off >>= 1) ss += __shfl_xor(ss, off);
    float nrm = fmaxf(sqrtf(ss), 1e-8f);
    if (lane == 0) row_sum[row] = 0.f;
    const float inv = 1.0f / nrm;
    unsigned int* dst = (unsigned int*)(fn8 + (size_t)row * D_DIM);
#pragma unroll
    for (int t = 0; t < 4; ++t)
        dst[lane + 64 * t] = pk_fp8x4(v[t].x * inv, v[t].y * inv, v[t].z * inv, v[t].w * inv);
}

// ---------------------------------------------------------------------------
// Raw workgroup barrier WITHOUT the __syncthreads() vmcnt(0) drain.
// Empty memory-clobber asm on both sides pins LDS/VMEM ops to their phase
// (prevents hipcc hoisting ds_reads across the barrier).
#define BARRIER() do { asm volatile("" ::: "memory"); \
    __builtin_amdgcn_s_barrier();                      \
    asm volatile("" ::: "memory"); } while (0)

// One A-fragment row (16 rows x 64 cols of C) against all 4 B fragments,
// both K=32 halves: 8 MFMAs. Two MROWs = one 16-MFMA phase cluster.
#define MROW(AF, I_) do { \
    acc[I_][0] = __builtin_amdgcn_mfma_f32_16x16x32_fp8_fp8(AF.x, bf[0].x, acc[I_][0], 0, 0, 0); \
    acc[I_][1] = __builtin_amdgcn_mfma_f32_16x16x32_fp8_fp8(AF.x, bf[1].x, acc[I_][1], 0, 0, 0); \
    acc[I_][2] = __builtin_amdgcn_mfma_f32_16x16x32_fp8_fp8(AF.x, bf[2].x, acc[I_][2], 0, 0, 0); \
    acc[I_][3] = __builtin_amdgcn_mfma_f32_16x16x32_fp8_fp8(AF.x, bf[3].x, acc[I_][3], 0, 0, 0); \
    acc[I_][0] = __builtin_amdgcn_mfma_f32_16x16x32_fp8_fp8(AF.y, bf[0].y, acc[I_][0], 0, 0, 0); \
    acc[I_][1] = __builtin_amdgcn_mfma_f32_16x16x32_fp8_fp8(AF.y, bf[1].y, acc[I_][1], 0, 0, 0); \
    acc[I_][2] = __builtin_amdgcn_mfma_f32_16x16x32_fp8_fp8(AF.y, bf[2].y, acc[I_][2], 0, 0, 0); \
    acc[I_][3] = __builtin_amdgcn_mfma_f32_16x16x32_fp8_fp8(AF.y, bf[3].y, acc[I_][3], 0, 0, 0); \
} while (0)

// ---------------------------------------------------------------------------
// Kernel 2 (r18): 128x256 ragged-triangular fp8 GEMM with a T3+T4-style
// counted-vmcnt phase pipeline (replaces the 2-barrier 128^2 structure that
// plateaued at 903 TF / MfmaUtil 35%).
//  * 8 waves (2M x 4N), per-wave 64x64 output, acc[4][4], BK=64 fp8 bytes
//  * 3-deep LDS buffer ring (A 8KB + B 16KB per buffer = 72 KB), prefetch
//    distance 2; main loop waits vmcnt(3) — NEVER drains to 0 (T4)
//  * 2 phases per K-step, 16-MFMA clusters, raw s_barrier + explicit
//    lgkmcnt(0), s_setprio(1) around MFMA (T5)
//  * staging swizzle + K-permuted b128 fragment reads carried over verbatim
//    (r6/r16: SQ_LDS_BANK_CONFLICT = 0)
//  * ragged-diagonal epilogue: same-128-block elements -> row-path only;
//    off-block upper -> row+col; off-block lower (odd-I left half) -> zeroed
//    (mirror tile covers that pair)
//  * fence-free done-counter loss tail unchanged (N_TILES=1056)
__global__ __launch_bounds__(512, 4) void simgemm_kernel(const unsigned char* __restrict__ fn8,
                                                         float* __restrict__ row_sum,
                                                         float* __restrict__ s_target,
                                                         unsigned int* __restrict__ done_cnt,
                                                         unsigned int* __restrict__ fin_cnt,
                                                         float* __restrict__ loss_acc,
                                                         float* __restrict__ out) {
    __shared__ __align__(16) unsigned char As[3][8 * 1024];    // 24 KiB
    __shared__ __align__(16) unsigned char Bs[3][16 * 1024];   // 48 KiB

    // ---- tile decode: t -> (I, J) with J in [I>>1, 32) ----
    // C(I) = 32*I - (I>>1)*((I-1)>>1) tiles precede row-tile I.
    const int t = blockIdx.x;
#define CSUM(i) (32 * (i) - ((i) >> 1) * (((i) - 1) >> 1))
    int I = 64 - (int)sqrtf(fmaxf(4096.f - 4.f * (float)t, 0.f)) - 2;
    if (I < 0) I = 0;
    if (I > 63) I = 63;
    while (CSUM(I + 1) <= t) ++I;
    while (CSUM(I) > t) --I;
    const int J = (I >> 1) + (t - CSUM(I));
    const int r0 = I * 128, c0 = J * 256;
    // tile holding sim[i, i+4096] for rows of I: J == (I>>1) + 16
    const bool haspair = (J == (I >> 1) + (HALF_N / 256));

    const int tid = threadIdx.x;
    const int w = tid >> 6, lane = tid & 63;
    const int q = lane >> 4, c16 = lane & 15;
    const int wm = w >> 2, wn = w & 3;       // wave grid 2 (M) x 4 (N)
    const int wm4 = wm * 4, wn4 = wn * 4;    // fragment chunk bases
    // staging: wave w stages A-chunk w (16 rows) and B-chunks 2w, 2w+1
    const int srow = lane >> 2;                               // row within chunk
    const int skoff = ((lane & 3) ^ ((srow >> 1) & 3)) * 16;  // rotate-within-row swizzle
    // fragment read byte offset within a chunk (kt-invariant)
    const int lfo = c16 * 64 + ((q ^ ((c16 >> 1) & 3)) * 16);

    const unsigned char* pa  = fn8 + (size_t)(r0 + w * 16 + srow) * D_DIM + skoff;
    const unsigned char* pb0 = fn8 + (size_t)(c0 + w * 32 + srow) * D_DIM + skoff;
    const unsigned char* pb1 = pb0 + 16 * D_DIM;

    f32x4 acc[4][4];
#pragma unroll
    for (int i = 0; i < 4; ++i)
#pragma unroll
        for (int j = 0; j < 4; ++j) acc[i][j] = (f32x4){0.f, 0.f, 0.f, 0.f};

    // ---- prologue: stage tiles 0 and 1 (3 loads/wave each) ----
    async_ld16(pa,       &As[0][w * 1024]);
    async_ld16(pb0,      &Bs[0][(2 * w) * 1024]);
    async_ld16(pb1,      &Bs[0][(2 * w + 1) * 1024]);
    async_ld16(pa  + 64, &As[1][w * 1024]);
    async_ld16(pb0 + 64, &Bs[1][(2 * w) * 1024]);
    async_ld16(pb1 + 64, &Bs[1][(2 * w + 1) * 1024]);
    pa += 128; pb0 += 128; pb1 += 128;
    asm volatile("s_waitcnt vmcnt(3)" ::: "memory");   // tile 0 landed; tile 1 in flight
    BARRIER();

    int cur = 0;
    for (int kt = 0; kt < 16; ++kt) {
        const bool pre = (kt < 14);          // stage tile kt+2?
        int nb = cur + 2; if (nb >= 3) nb -= 3;
        long2_ bf[4], a0, a1;
        // ---- phase 0: read B frags + A frags 0,1; issue 2 stage loads ----
        bf[0] = *(const long2_*)&Bs[cur][(wn4 + 0) * 1024 + lfo];
        bf[1] = *(const long2_*)&Bs[cur][(wn4 + 1) * 1024 + lfo];
        bf[2] = *(const long2_*)&Bs[cur][(wn4 + 2) * 1024 + lfo];
        bf[3] = *(const long2_*)&Bs[cur][(wn4 + 3) * 1024 + lfo];
        a0 = *(const long2_*)&As[cur][(wm4 + 0) * 1024 + lfo];
        a1 = *(const long2_*)&As[cur][(wm4 + 1) * 1024 + lfo];
        if (pre) {
            async_ld16(pa,  &As[nb][w * 1024]);
            async_ld16(pb0, &Bs[nb][(2 * w) * 1024]);
        }
        BARRIER();
        asm volatile("s_waitcnt lgkmcnt(0)" ::: "memory");
        __builtin_amdgcn_s_setprio(1);
        MROW(a0, 0);
        MROW(a1, 1);
        __builtin_amdgcn_s_setprio(0);
        BARRIER();
        // ---- phase 1: read A frags 2,3; issue 3rd stage load ----
        a0 = *(const long2_*)&As[cur][(wm4 + 2) * 1024 + lfo];
        a1 = *(const long2_*)&As[cur][(wm4 + 3) * 1024 + lfo];
        if (pre) {
            async_ld16(pb1, &Bs[nb][(2 * w + 1) * 1024]);
            pa += 64; pb0 += 64; pb1 += 64;
        }
        BARRIER();
        asm volatile("s_waitcnt lgkmcnt(0)" ::: "memory");
        __builtin_amdgcn_s_setprio(1);
        MROW(a0, 2);
        MROW(a1, 3);
        __builtin_amdgcn_s_setprio(0);
        // counted wait: tile kt+1 landed (tile kt+2's 3 loads stay in flight)
        if (kt < 14) {
            asm volatile("s_waitcnt vmcnt(3)" ::: "memory");
            BARRIER();
        } else if (kt == 14) {
            asm volatile("s_waitcnt vmcnt(0)" ::: "memory");
            BARRIER();
        }
        cur = (cur == 2) ? 0 : cur + 1;
    }

    // ---- epilogue: e = exp(sim - M); ragged-diagonal pair accounting ----
    // same128 (element inside its diagonal 128-square): row-path only
    //   (both (r,c) and (c,r) live in this tile).
    // off-block & grow<gcol: row-path AND col-path (mirror never computed).
    // off-block & grow>gcol: zero (mirror tile computes the pair).
    float cs[4] = {0.f, 0.f, 0.f, 0.f};
#pragma unroll
    for (int i = 0; i < 4; ++i) {
        const int growb = r0 + wm * 64 + i * 16 + q * 4;
#pragma unroll
        for (int r = 0; r < 4; ++r) {
            const int grow = growb + r;
            float s = 0.f;
#pragma unroll
            for (int j = 0; j < 4; ++j) {
                const int gcol = c0 + wn * 64 + j * 16 + c16;
                float sim = acc[i][j][r] * INV_T;
                float e = __expf(sim - INV_T);
                const bool same128 = (((grow ^ gcol) >> 7) == 0);
                if (grow == gcol || (!same128 && grow > gcol)) e = 0.f;
                if (haspair && gcol == grow + HALF_N) {
                    __hip_atomic_store(&s_target[grow], sim, __ATOMIC_RELAXED,
                                       __HIP_MEMORY_SCOPE_AGENT);
                    __hip_atomic_store(&s_target[gcol], sim, __ATOMIC_RELAXED,
                                       __HIP_MEMORY_SCOPE_AGENT);
                }
                s += e;
                cs[j] += same128 ? 0.f : e;
            }
            s += __shfl_xor(s, 1);
            s += __shfl_xor(s, 2);
            s += __shfl_xor(s, 4);
            s += __shfl_xor(s, 8);
            if (c16 == 0) atomicAdd(&row_sum[grow], s);
        }
    }
    // col path: reduce each cs[j] across the 4 quads, one atomic/column.
    // (straddle tiles contribute zeros where appropriate — harmless)
#pragma unroll
    for (int j = 0; j < 4; ++j) {
        float s = cs[j];
        s += __shfl_xor(s, 16);
        s += __shfl_xor(s, 32);
        if (q == 0) atomicAdd(&row_sum[c0 + wn * 64 + j * 16 + c16], s);
    }

    // ---- fence-free fused loss tail, 8-way parallel ----
    __syncthreads();   // drains vmcnt(0): all this block's atomics performed
    __shared__ unsigned int my_ord;
    if (tid == 0)
        my_ord = __hip_atomic_fetch_add(done_cnt, 1u, __ATOMIC_RELAXED,
                                        __HIP_MEMORY_SCOPE_AGENT);
    __syncthreads();
    const unsigned int ord = my_ord;
    if (ord >= N_TILES - N_RED) {
        if (tid == 0) {
            while (__hip_atomic_load(done_cnt, __ATOMIC_RELAXED,
                                     __HIP_MEMORY_SCOPE_AGENT) < N_TILES)
                __builtin_amdgcn_s_sleep(1);
        }
        __syncthreads();
        const int slice = (int)(ord - (N_TILES - N_RED));   // 0..7
        const int base_row = slice * (N_ROWS / N_RED) + tid * 2;   // 1024 rows, 2/thread
        float rv0 = __hip_atomic_load(&row_sum[base_row + 0], __ATOMIC_RELAXED,
                                      __HIP_MEMORY_SCOPE_AGENT);
        float rv1 = __hip_atomic_load(&row_sum[base_row + 1], __ATOMIC_RELAXED,
                                      __HIP_MEMORY_SCOPE_AGENT);
        float sv0 = __hip_atomic_load(&s_target[base_row + 0], __ATOMIC_RELAXED,
                                      __HIP_MEMORY_SCOPE_AGENT);
        float sv1 = __hip_atomic_load(&s_target[base_row + 1], __ATOMIC_RELAXED,
                                      __HIP_MEMORY_SCOPE_AGENT);
        float local = __logf(rv0) - sv0 + __logf(rv1) - sv1;
#pragma unroll
        for (int off = 32; off; off >>= 1) local += __shfl_xor(local, off);
        __shared__ float part[8];
        if ((tid & 63) == 0) part[w] = local;
        __syncthreads();
        if (tid == 0) {
            float bsum = 0.f;
#pragma unroll
            for (int k = 0; k < 8; ++k) bsum += part[k];
            __hip_atomic_fetch_add(loss_acc, bsum, __ATOMIC_RELAXED,
                                   __HIP_MEMORY_SCOPE_AGENT);
            unsigned int f = __hip_atomic_fetch_add(fin_cnt, 1u, __ATOMIC_ACQ_REL,
                                                    __HIP_MEMORY_SCOPE_AGENT);
            if (f == N_RED - 1) {
                float accv = __hip_atomic_load(loss_acc, __ATOMIC_RELAXED,
                                               __HIP_MEMORY_SCOPE_AGENT);
                out[0] = INV_T + accv * (1.0f / N_ROWS);
            }
        }
    }
}

// ---------------------------------------------------------------------------
extern "C" void kernel_launch(void* const* d_in, const int* in_sizes, int n_in,
                              void* d_out, int out_size, void* d_ws, size_t ws_size,
                              hipStream_t stream) {
    const float* feat = (const float*)d_in[0];
    float* out = (float*)d_out;
    char* ws = (char*)d_ws;

    unsigned char* fn8 = (unsigned char*)ws;                  // 8192*1024 fp8 = 8 MiB
    size_t off = (size_t)N_ROWS * D_DIM;
    float* row_sum = (float*)(ws + off);   off += N_ROWS * sizeof(float);
    float* s_target = (float*)(ws + off);  off += N_ROWS * sizeof(float);
    unsigned int* done_cnt = (unsigned int*)(ws + off);  off += sizeof(unsigned int);
    unsigned int* fin_cnt = (unsigned int*)(ws + off);   off += sizeof(unsigned int);
    float* loss_acc = (float*)(ws + off);

    norm_kernel<<<N_ROWS / 4, 256, 0, stream>>>(feat, fn8, row_sum, done_cnt, fin_cnt, loss_acc);
    simgemm_kernel<<<N_TILES, 512, 0, stream>>>(fn8, row_sum, s_target, done_cnt, fin_cnt, loss_acc, out);
}

// Round 2
// 142.215 us; speedup vs baseline: 1.0798x; 1.0798x over previous
//
#include <hip/hip_runtime.h>
#include <hip/hip_bf16.h>

// Problem constants
#define N_ROWS 8192
#define D_DIM  1024
#define HALF_N 4096
#define N_TILES 2080             // 64*65/2 upper-triangular 128x128 tile pairs
#define N_RED  8                 // parallel loss-reduction blocks
constexpr float INV_T = 1.0f / 0.07f;   // 14.2857143 — also the fixed softmax max M

typedef __attribute__((ext_vector_type(4))) float f32x4;
typedef __attribute__((ext_vector_type(2))) long long2_;   // 16B = one ds_read_b128

// async global->LDS, 16B/lane. LDS dest is wave-uniform base + lane*16.
__device__ __forceinline__ void async_ld16(const void* g, void* lds) {
    __builtin_amdgcn_global_load_lds(
        (const __attribute__((address_space(1))) void*)g,
        (__attribute__((address_space(3))) void*)lds,
        16, 0, 0);
}

// pack 4 floats -> 4 OCP e4m3 bytes in one dword
__device__ __forceinline__ unsigned int pk_fp8x4(float a, float b, float c, float d) {
    int v = __builtin_amdgcn_cvt_pk_fp8_f32(a, b, 0, false);   // bytes 0,1
    v = __builtin_amdgcn_cvt_pk_fp8_f32(c, d, v, true);        // bytes 2,3
    return (unsigned int)v;
}

// ---------------------------------------------------------------------------
// Kernel 1: row norms + fp8 e4m3 normalized copy + zeroing of row_sum and the
// handshake cells. One wave per row. (unchanged — measured fine)
__global__ __launch_bounds__(256) void norm_kernel(const float* __restrict__ feat,
                                                   unsigned char* __restrict__ fn8,
                                                   float* __restrict__ row_sum,
                                                   unsigned int* __restrict__ done_cnt,
                                                   unsigned int* __restrict__ fin_cnt,
                                                   float* __restrict__ loss_acc) {
    const int w = threadIdx.x >> 6, lane = threadIdx.x & 63;
    const int row = blockIdx.x * 4 + w;
    if (blockIdx.x == 0 && threadIdx.x == 0) {
        *done_cnt = 0u;
        *fin_cnt = 0u;
        *loss_acc = 0.f;
    }
    const float4* src = (const float4*)(feat + (size_t)row * D_DIM);
    float4 v[4];
    float ss = 0.f;
#pragma unroll
    for (int t = 0; t < 4; ++t) {
        v[t] = src[lane + 64 * t];
        ss += v[t].x * v[t].x + v[t].y * v[t].y + v[t].z * v[t].z + v[t].w * v[t].w;
    }
#pragma unroll
    for (int off = 32; off; off >>= 1) ss += __shfl_xor(ss, off);
    float nrm = fmaxf(sqrtf(ss), 1e-8f);
    if (lane == 0) row_sum[row] = 0.f;
    const float inv = 1.0f / nrm;
    unsigned int* dst = (unsigned int*)(fn8 + (size_t)row * D_DIM);
#pragma unroll
    for (int t = 0; t < 4; ++t)
        dst[lane + 64 * t] = pk_fp8x4(v[t].x * inv, v[t].y * inv, v[t].z * inv, v[t].w * inv);
}

// ---------------------------------------------------------------------------
// Raw workgroup barrier WITHOUT the __syncthreads() vmcnt(0) drain.
#define BARRIER() do { asm volatile("" ::: "memory"); \
    __builtin_amdgcn_s_barrier();                      \
    asm volatile("" ::: "memory"); } while (0)

// One A-fragment (16 rows x 64 cols of C) against all 4 B fragments,
// both K=32 halves: 8 MFMAs. Two MROWs = one 16-MFMA cluster.
#define MROW(AF, I_) do { \
    acc[I_][0] = __builtin_amdgcn_mfma_f32_16x16x32_fp8_fp8(AF.x, bf[0].x, acc[I_][0], 0, 0, 0); \
    acc[I_][1] = __builtin_amdgcn_mfma_f32_16x16x32_fp8_fp8(AF.x, bf[1].x, acc[I_][1], 0, 0, 0); \
    acc[I_][2] = __builtin_amdgcn_mfma_f32_16x16x32_fp8_fp8(AF.x, bf[2].x, acc[I_][2], 0, 0, 0); \
    acc[I_][3] = __builtin_amdgcn_mfma_f32_16x16x32_fp8_fp8(AF.x, bf[3].x, acc[I_][3], 0, 0, 0); \
    acc[I_][0] = __builtin_amdgcn_mfma_f32_16x16x32_fp8_fp8(AF.y, bf[0].y, acc[I_][0], 0, 0, 0); \
    acc[I_][1] = __builtin_amdgcn_mfma_f32_16x16x32_fp8_fp8(AF.y, bf[1].y, acc[I_][1], 0, 0, 0); \
    acc[I_][2] = __builtin_amdgcn_mfma_f32_16x16x32_fp8_fp8(AF.y, bf[2].y, acc[I_][2], 0, 0, 0); \
    acc[I_][3] = __builtin_amdgcn_mfma_f32_16x16x32_fp8_fp8(AF.y, bf[3].y, acc[I_][3], 0, 0, 0); \
} while (0)

// ---------------------------------------------------------------------------
// Kernel 2 (r19): 128x128 triangular fp8 GEMM (2080 tiles, 4 waves — the
// r16 geometry that load-balances at 1.107x) with the r18 counted-vmcnt
// pipeline that measured MfmaUtil ~47% in full rounds:
//  * 3-deep LDS ring (A 8KB + B 8KB per buf = 48 KB) -> 3 blocks/CU,
//    capacity 768 blocks, 2080/768 = 2.71 -> near-perfect makespan
//  * stage tile kt+2 each step; end-of-step s_waitcnt vmcnt(4) (tile kt+1
//    landed, kt+2 stays in flight — NEVER drains to 0 in the main loop)
//  * ONE raw s_barrier per K-step (anti-dep + staging handshake each need
//    exactly one; 3 co-resident blocks cover intra-block stalls)
//  * 2 MFMA clusters of 16 per step, lgkmcnt(0) + setprio(1) around each
//  * staging swizzle + K-permuted b128 fragment reads verbatim from r16
//    (SQ_LDS_BANK_CONFLICT = 0); epilogue + fence-free loss tail verbatim
__global__ __launch_bounds__(256, 3) void simgemm_kernel(const unsigned char* __restrict__ fn8,
                                                         float* __restrict__ row_sum,
                                                         float* __restrict__ s_target,
                                                         unsigned int* __restrict__ done_cnt,
                                                         unsigned int* __restrict__ fin_cnt,
                                                         float* __restrict__ loss_acc,
                                                         float* __restrict__ out) {
    __shared__ __align__(16) unsigned char As[3][8 * 1024];   // 24 KiB
    __shared__ __align__(16) unsigned char Bs[3][8 * 1024];   // 24 KiB
    // triangular decode: t -> (I,J), I<=J
    const int t = blockIdx.x;
    int a = (int)((sqrtf(8.f * (float)t + 1.f) - 1.f) * 0.5f);
    while ((a + 1) * (a + 2) / 2 <= t) ++a;
    while (a * (a + 1) / 2 > t) --a;
    const int I = t - a * (a + 1) / 2;   // row-tile index (<= J)
    const int J = a;                     // col-tile index
    const int r0 = I * 128, c0 = J * 128;
    const bool isdiag = (I == J);
    const bool haspair = (J == I + 32);  // contains sim[i, i+4096] for rows in I

    const int tid = threadIdx.x;
    const int w = tid >> 6, lane = tid & 63;
    const int q = lane >> 4, c16 = lane & 15;
    const int wr = (w >> 1) * 64;  // wave's row base within tile
    const int wc = (w & 1) * 64;   // wave's col base within tile
    const int wr4 = (w >> 1) * 4;  // wave's A chunk base (16-row chunks)
    const int wc4 = (w & 1) * 4;   // wave's B chunk base
    // staging: wave w stages chunks 2w, 2w+1 (rows w*32 .. w*32+31).
    const int srow = lane >> 2;                               // row within chunk
    const int skoff = ((lane & 3) ^ ((srow >> 1) & 3)) * 16;  // swizzled unit byte offset
    // fragment read byte offset within a chunk (kt-invariant)
    const int lfo = c16 * 64 + ((q ^ ((c16 >> 1) & 3)) * 16);

    const unsigned char* pa0 = fn8 + (size_t)(r0 + w * 32 + srow) * D_DIM + skoff;
    const unsigned char* pa1 = pa0 + 16 * D_DIM;
    const unsigned char* pb0 = fn8 + (size_t)(c0 + w * 32 + srow) * D_DIM + skoff;
    const unsigned char* pb1 = pb0 + 16 * D_DIM;

    f32x4 acc[4][4];
#pragma unroll
    for (int i = 0; i < 4; ++i)
#pragma unroll
        for (int j = 0; j < 4; ++j) acc[i][j] = (f32x4){0.f, 0.f, 0.f, 0.f};

    // ---- prologue: stage tiles 0 and 1 (4 loads/wave each) ----
    async_ld16(pa0,      &As[0][(w * 2 + 0) * 1024]);
    async_ld16(pa1,      &As[0][(w * 2 + 1) * 1024]);
    async_ld16(pb0,      &Bs[0][(w * 2 + 0) * 1024]);
    async_ld16(pb1,      &Bs[0][(w * 2 + 1) * 1024]);
    async_ld16(pa0 + 64, &As[1][(w * 2 + 0) * 1024]);
    async_ld16(pa1 + 64, &As[1][(w * 2 + 1) * 1024]);
    async_ld16(pb0 + 64, &Bs[1][(w * 2 + 0) * 1024]);
    async_ld16(pb1 + 64, &Bs[1][(w * 2 + 1) * 1024]);
    asm volatile("s_waitcnt vmcnt(4)" ::: "memory");   // tile 0 landed; tile 1 in flight
    BARRIER();

    int cur = 0;
    for (int kt = 0; kt < 16; ++kt) {
        int nb = cur + 2; if (nb >= 3) nb -= 3;
        long2_ bf[4], a0, a1;
        // fragment reads for cluster 1 + all B frags
        bf[0] = *(const long2_*)&Bs[cur][(wc4 + 0) * 1024 + lfo];
        bf[1] = *(const long2_*)&Bs[cur][(wc4 + 1) * 1024 + lfo];
        bf[2] = *(const long2_*)&Bs[cur][(wc4 + 2) * 1024 + lfo];
        bf[3] = *(const long2_*)&Bs[cur][(wc4 + 3) * 1024 + lfo];
        a0 = *(const long2_*)&As[cur][(wr4 + 0) * 1024 + lfo];
        a1 = *(const long2_*)&As[cur][(wr4 + 1) * 1024 + lfo];
        // stage tile kt+2 into nb (its old contents were last read at step
        // kt-1, whose lgkmcnt(0) preceded the barrier we just crossed)
        if (kt < 14) {
            const int off = (kt + 2) * 64;
            async_ld16(pa0 + off, &As[nb][(w * 2 + 0) * 1024]);
            async_ld16(pa1 + off, &As[nb][(w * 2 + 1) * 1024]);
            async_ld16(pb0 + off, &Bs[nb][(w * 2 + 0) * 1024]);
            async_ld16(pb1 + off, &Bs[nb][(w * 2 + 1) * 1024]);
        }
        asm volatile("s_waitcnt lgkmcnt(0)" ::: "memory");
        __builtin_amdgcn_s_setprio(1);
        MROW(a0, 0);
        MROW(a1, 1);
        __builtin_amdgcn_s_setprio(0);
        a0 = *(const long2_*)&As[cur][(wr4 + 2) * 1024 + lfo];
        a1 = *(const long2_*)&As[cur][(wr4 + 3) * 1024 + lfo];
        asm volatile("s_waitcnt lgkmcnt(0)" ::: "memory");
        __builtin_amdgcn_s_setprio(1);
        MROW(a0, 2);
        MROW(a1, 3);
        __builtin_amdgcn_s_setprio(0);
        // counted wait: tile kt+1 landed; tile kt+2's 4 loads stay in flight
        if (kt < 14) {
            asm volatile("s_waitcnt vmcnt(4)" ::: "memory");
            BARRIER();
        } else if (kt == 14) {
            asm volatile("s_waitcnt vmcnt(0)" ::: "memory");
            BARRIER();
        }
        cur = (cur == 2) ? 0 : cur + 1;
    }

    // epilogue: e = exp(sim - M); rows-in-I sums + (I<J) cols-in-J sums.
    float cs[4] = {0.f, 0.f, 0.f, 0.f};   // per-j column partial sums
#pragma unroll
    for (int i = 0; i < 4; ++i) {
        const int growb = r0 + wr + i * 16 + q * 4;
#pragma unroll
        for (int r = 0; r < 4; ++r) {
            const int grow = growb + r;
            float s = 0.f;
#pragma unroll
            for (int j = 0; j < 4; ++j) {
                const int gcol = c0 + wc + j * 16 + c16;
                float sim = acc[i][j][r] * INV_T;
                float e = __expf(sim - INV_T);
                if (isdiag && grow == gcol) e = 0.f;   // diagonal mask
                if (haspair && gcol == grow + HALF_N) {
                    __hip_atomic_store(&s_target[grow], sim, __ATOMIC_RELAXED,
                                       __HIP_MEMORY_SCOPE_AGENT);
                    __hip_atomic_store(&s_target[gcol], sim, __ATOMIC_RELAXED,
                                       __HIP_MEMORY_SCOPE_AGENT);
                }
                s += e;
                cs[j] += e;
            }
            // row path: reduce over the 16 col-lanes of the quad
            s += __shfl_xor(s, 1);
            s += __shfl_xor(s, 2);
            s += __shfl_xor(s, 4);
            s += __shfl_xor(s, 8);
            if (c16 == 0) atomicAdd(&row_sum[grow], s);
        }
    }
    if (!isdiag) {
        // col path: reduce each cs[j] across the 4 quads, one atomic/column
#pragma unroll
        for (int j = 0; j < 4; ++j) {
            float s = cs[j];
            s += __shfl_xor(s, 16);
            s += __shfl_xor(s, 32);
            if (q == 0) atomicAdd(&row_sum[c0 + wc + j * 16 + c16], s);
        }
    }

    // ---- fence-free fused loss tail, 8-way parallel ----
    __syncthreads();   // all waves' vmem drained (compiler emits vmcnt(0) here)
    __shared__ unsigned int my_ord;
    if (tid == 0)
        my_ord = __hip_atomic_fetch_add(done_cnt, 1u, __ATOMIC_RELAXED,
                                        __HIP_MEMORY_SCOPE_AGENT);
    __syncthreads();
    const unsigned int ord = my_ord;
    if (ord >= N_TILES - N_RED) {
        // wait until ALL 2080 blocks have signalled (their sums are in).
        if (tid == 0) {
            while (__hip_atomic_load(done_cnt, __ATOMIC_RELAXED,
                                     __HIP_MEMORY_SCOPE_AGENT) < N_TILES)
                __builtin_amdgcn_s_sleep(1);
        }
        __syncthreads();
        const int slice = (int)(ord - (N_TILES - N_RED));   // 0..7
        const int base_row = slice * (N_ROWS / N_RED) + tid * 4;
        float rv[4], sv[4];
#pragma unroll
        for (int u = 0; u < 4; ++u) {
            rv[u] = __hip_atomic_load(&row_sum[base_row + u], __ATOMIC_RELAXED,
                                      __HIP_MEMORY_SCOPE_AGENT);
            sv[u] = __hip_atomic_load(&s_target[base_row + u], __ATOMIC_RELAXED,
                                      __HIP_MEMORY_SCOPE_AGENT);
        }
        float local = 0.f;
#pragma unroll
        for (int u = 0; u < 4; ++u)
            local += __logf(rv[u]) - sv[u];
#pragma unroll
        for (int off = 32; off; off >>= 1) local += __shfl_xor(local, off);
        __shared__ float part[4];
        if ((tid & 63) == 0) part[tid >> 6] = local;
        __syncthreads();
        if (tid == 0) {
            float bsum = part[0] + part[1] + part[2] + part[3];
            __hip_atomic_fetch_add(loss_acc, bsum, __ATOMIC_RELAXED,
                                   __HIP_MEMORY_SCOPE_AGENT);
            unsigned int f = __hip_atomic_fetch_add(fin_cnt, 1u, __ATOMIC_ACQ_REL,
                                                    __HIP_MEMORY_SCOPE_AGENT);
            if (f == N_RED - 1) {
                float accv = __hip_atomic_load(loss_acc, __ATOMIC_RELAXED,
                                               __HIP_MEMORY_SCOPE_AGENT);
                out[0] = INV_T + accv * (1.0f / N_ROWS);
            }
        }
    }
}

// ---------------------------------------------------------------------------
extern "C" void kernel_launch(void* const* d_in, const int* in_sizes, int n_in,
                              void* d_out, int out_size, void* d_ws, size_t ws_size,
                              hipStream_t stream) {
    const float* feat = (const float*)d_in[0];
    float* out = (float*)d_out;
    char* ws = (char*)d_ws;

    unsigned char* fn8 = (unsigned char*)ws;                  // 8192*1024 fp8 = 8 MiB
    size_t off = (size_t)N_ROWS * D_DIM;
    float* row_sum = (float*)(ws + off);   off += N_ROWS * sizeof(float);
    float* s_target = (float*)(ws + off);  off += N_ROWS * sizeof(float);
    unsigned int* done_cnt = (unsigned int*)(ws + off);  off += sizeof(unsigned int);
    unsigned int* fin_cnt = (unsigned int*)(ws + off);   off += sizeof(unsigned int);
    float* loss_acc = (float*)(ws + off);

    norm_kernel<<<N_ROWS / 4, 256, 0, stream>>>(feat, fn8, row_sum, done_cnt, fin_cnt, loss_acc);
    simgemm_kernel<<<N_TILES, 256, 0, stream>>>(fn8, row_sum, s_target, done_cnt, fin_cnt, loss_acc, out);
}